// Round 1
// baseline (152.595 us; speedup 1.0000x reference)
//
#include <hip/hip_runtime.h>

#define Bsz 4
#define Nn  256
#define OBSD 40
#define ACTD 8
#define HEADS 8
#define DIMD 32
#define Td  256
#define R1  2   // rows per block in k_emb
#define R2  4   // m-rows per block in k_fused

#define FMA4(accr, s, wv) \
    (accr).x = fmaf((s), (wv).x, (accr).x); \
    (accr).y = fmaf((s), (wv).y, (accr).y); \
    (accr).z = fmaf((s), (wv).z, (accr).z); \
    (accr).w = fmaf((s), (wv).w, (accr).w)

// K1: emb = relu(relu(obs @ We1 + be1) @ We2 + be2), R1=2 rows per block.
// grid = 512 blocks x 512 threads, launch_bounds(512,4) -> 2 blocks/CU = 4 waves/SIMD.
// Blocks 0/1 zero snh/shid; blocks 2..25 warm Wn/Wh/Wl into L2/L3 for K2/K3.
__global__ __launch_bounds__(512, 4) void k_emb(
                      const float* __restrict__ x,
                      const float* __restrict__ We1, const float* __restrict__ be1,
                      const float* __restrict__ We2, const float* __restrict__ be2,
                      const float* __restrict__ Wn,  const float* __restrict__ Wh,
                      const float* __restrict__ Wl,
                      float* __restrict__ emb,
                      float* __restrict__ snh, float* __restrict__ shid,
                      float* __restrict__ dump) {
    int g = blockIdx.x;                  // 0..511
    int t = threadIdx.x;                 // 0..511
    int row0 = g * R1;
    int b = row0 >> 8;
    int n0 = row0 & 255;
    if (g == 0)      { for (int i = t; i < Bsz * Td; i += 512) snh[i]  = 0.f; }
    else if (g == 1) { for (int i = t; i < Bsz * Td; i += 512) shid[i] = 0.f; }

    __shared__ float2 obs_t[OBSD];       // 2 rows per obs-channel
    __shared__ float2 h1_t[Td];          // 2 rows per hidden channel
    __shared__ float4 part[8][R1][64];   // [wave][row][colgroup] partials (16 KB)
    if (t < R1 * OBSD) {                 // 80 threads
        int r = t & 1, k = t >> 1;
        ((float*)&obs_t[k])[r] = x[(b * (Nn + 1) + n0 + r) * OBSD + k];
    }
    __syncthreads();

    // Layer 1 (K=40): threads 0..255 own one column each, 8-deep prefetch.
    if (t < Td) {
        float bias1 = be1[t];
        float a0 = bias1, a1 = bias1;
        float wbuf[8];
#pragma unroll
        for (int p = 0; p < 8; ++p) wbuf[p] = We1[p * Td + t];
#pragma unroll
        for (int k = 0; k < OBSD; ++k) {
            float w = wbuf[k & 7];
            if (k + 8 < OBSD) wbuf[k & 7] = We1[(k + 8) * Td + t];
            float2 ov = obs_t[k];
            a0 = fmaf(ov.x, w, a0);
            a1 = fmaf(ov.y, w, a1);
        }
        h1_t[t] = make_float2(fmaxf(a0, 0.f), fmaxf(a1, 0.f));
    }
    __syncthreads();

    // Layer 2: wave wv (0..7) handles k in [32wv, +32); lane c owns cols 4c..4c+3.
    int wv = t >> 6, c = t & 63;
    {
        float4 a2[R1] = {};
        float4 buf[8];
#pragma unroll
        for (int p = 0; p < 8; ++p)
            buf[p] = *(const float4*)(We2 + ((wv << 5) + p) * Td + 4 * c);
#pragma unroll
        for (int i = 0; i < 32; ++i) {
            int k = (wv << 5) + i;
            float4 wvv = buf[i & 7];
            if (i + 8 < 32)
                buf[i & 7] = *(const float4*)(We2 + (k + 8) * Td + 4 * c);
            float2 hv = h1_t[k];
            FMA4(a2[0], hv.x, wvv);
            FMA4(a2[1], hv.y, wvv);
        }
#pragma unroll
        for (int r = 0; r < R1; ++r) part[wv][r][c] = a2[r];
    }
    __syncthreads();

    if (t < Td) {
        int c2 = t >> 2, j = t & 3;
#pragma unroll
        for (int r = 0; r < R1; ++r) {
            float v = be2[t];
#pragma unroll
            for (int w2 = 0; w2 < 8; ++w2) v += ((const float*)&part[w2][r][c2])[j];
            emb[(row0 + r) * Td + t] = fmaxf(v, 0.f);
        }
    }

    // Warm Wn/Wh/Wl (768 KB total) into L2/L3 for k_fused/k_final.
    // 24 blocks x 512 threads x 4 float4 = 49152 float4 = exactly Wn+Wh+Wl.
    if (g >= 2 && g < 26) {
        int L = (g - 2) * 512 + t;       // 0..12287
        int q = L << 2;                  // float4 index, 0..49151
        const float4* src;
        if (q < 16384)      src = (const float4*)Wn + q;
        else if (q < 32768) src = (const float4*)Wh + (q - 16384);
        else                src = (const float4*)Wl + (q - 32768);
        float s = 0.f;
#pragma unroll
        for (int p2 = 0; p2 < 4; ++p2) {
            float4 v = src[p2];
            s += v.x + v.y + v.z + v.w;
        }
        dump[L] = s;                     // real store: keeps loads alive, no DCE
    }
}

// K2: fused ne + Wn/Wh column-sum, R2=4 m-rows per block.
// grid = (N/R2, B) = (64, 4) = 256 blocks x 1024 threads (16 waves/CU = 4/SIMD).
// Same per-block L2 traffic as the 512-thread version; 2x the latency hiding.
__global__ __launch_bounds__(1024, 4) void k_fused(
                        const float* __restrict__ adj, const float* __restrict__ emb,
                        const float* __restrict__ Wn, const float* __restrict__ bn,
                        const float* __restrict__ Wh, const float* __restrict__ bh,
                        float* __restrict__ snh, float* __restrict__ shid) {
    int g = blockIdx.x, b = blockIdx.y;
    int t = threadIdx.x;                 // 0..1023
    int m0 = g * R2;
    __shared__ float4 arow_t[Nn];        // 4 KB
    __shared__ float4 nrow_t[Td];        // 4 KB
    __shared__ float4 partN[16][R2][64]; // 64 KB
    __shared__ float4 partH[16][R2][64]; // 64 KB  (total 136 KB < 160 KB)
    if (t < Td)
        arow_t[t] = make_float4(adj[(m0 + 0) * Nn + t], adj[(m0 + 1) * Nn + t],
                                adj[(m0 + 2) * Nn + t], adj[(m0 + 3) * Nn + t]);
    __syncthreads();

    int wv = t >> 6, c = t & 63;         // wv 0..15
    const float* eb = emb + b * Nn * Td;

    // Phase 1: ne. Wave wv sums n in [16wv, +16); 8-deep prefetch.
    {
        float4 aN[R2] = {};
        float4 buf[8];
#pragma unroll
        for (int p = 0; p < 8; ++p)
            buf[p] = *(const float4*)(eb + ((wv << 4) + p) * Td + 4 * c);
#pragma unroll
        for (int i = 0; i < 16; ++i) {
            int n = (wv << 4) + i;
            float4 ev = buf[i & 7];
            if (i + 8 < 16)
                buf[i & 7] = *(const float4*)(eb + (n + 8) * Td + 4 * c);
            float4 ar = arow_t[n];
            FMA4(aN[0], ar.x, ev);
            FMA4(aN[1], ar.y, ev);
            FMA4(aN[2], ar.z, ev);
            FMA4(aN[3], ar.w, ev);
        }
#pragma unroll
        for (int r = 0; r < R2; ++r) partN[wv][r][c] = aN[r];
    }
    __syncthreads();
    if (t < Td) {
        int c2 = t >> 2, j = t & 3;
        float nr[R2];
#pragma unroll
        for (int r = 0; r < R2; ++r) {
            float v = 0.f;
#pragma unroll
            for (int w2 = 0; w2 < 16; ++w2) v += ((const float*)&partN[w2][r][c2])[j];
            nr[r] = v;
        }
        nrow_t[t] = make_float4(nr[0], nr[1], nr[2], nr[3]);
    }
    __syncthreads();

    // Phase 2: Wn/Wh dual stream; wave wv handles k in [16wv, +16); 4+4 prefetch.
    {
        float4 sN[R2] = {};
        float4 sH[R2] = {};
        float4 bufN[4], bufH[4];
#pragma unroll
        for (int p = 0; p < 4; ++p) {
            int k = (wv << 4) + p;
            bufN[p] = *(const float4*)(Wn + k * Td + 4 * c);
            bufH[p] = *(const float4*)(Wh + k * Td + 4 * c);
        }
#pragma unroll
        for (int i = 0; i < 16; ++i) {
            int k = (wv << 4) + i;
            float4 wn4 = bufN[i & 3];
            float4 wh4 = bufH[i & 3];
            if (i + 4 < 16) {
                bufN[i & 3] = *(const float4*)(Wn + (k + 4) * Td + 4 * c);
                bufH[i & 3] = *(const float4*)(Wh + (k + 4) * Td + 4 * c);
            }
            float4 nv = nrow_t[k];
            FMA4(sN[0], nv.x, wn4);  FMA4(sH[0], nv.x, wh4);
            FMA4(sN[1], nv.y, wn4);  FMA4(sH[1], nv.y, wh4);
            FMA4(sN[2], nv.z, wn4);  FMA4(sH[2], nv.z, wh4);
            FMA4(sN[3], nv.w, wn4);  FMA4(sH[3], nv.w, wh4);
        }
#pragma unroll
        for (int r = 0; r < R2; ++r) { partN[wv][r][c] = sN[r]; partH[wv][r][c] = sH[r]; }
    }
    __syncthreads();

    // Reduce over 16 waves (pre-relu), bias, relu, sum rows, one atomic per col.
    if (t < Td) {
        int c2 = t >> 2, j = t & 3;
        float bnt = bn[t], bht = bh[t];
        float rs1 = 0.f, rs2 = 0.f;
#pragma unroll
        for (int r = 0; r < R2; ++r) {
            float v1 = bnt, v2 = bht;
#pragma unroll
            for (int w2 = 0; w2 < 16; ++w2) {
                v1 += ((const float*)&partN[w2][r][c2])[j];
                v2 += ((const float*)&partH[w2][r][c2])[j];
            }
            rs1 += fmaxf(v1, 0.f);
            rs2 += fmaxf(v2, 0.f);
        }
        atomicAdd(&snh[b * Td + t], rs1);
        atomicAdd(&shid[b * Td + t], rs2);
    }
}

// K3: per-batch target row -> ah -> softmax over DIM per head -> mean -> Wa
// 512 threads: 8-way k-split on the Wl reduction (was 4).
__global__ __launch_bounds__(512, 1) void k_final(
                        const float* __restrict__ x, const float* __restrict__ emb,
                        const float* __restrict__ Wl, const float* __restrict__ bl,
                        const float* __restrict__ snh, const float* __restrict__ shid,
                        const float* __restrict__ Wa, const float* __restrict__ ba,
                        float* __restrict__ out) {
    int b = blockIdx.x;
    int t = threadIdx.x;                 // 0..511
    int tgt = (int)x[(b * (Nn + 1) + Nn) * OBSD + 0];
    tgt = tgt < 0 ? 0 : (tgt > Nn - 1 ? Nn - 1 : tgt);
    __shared__ float erow[Td], lg[Td], p[Td], od[DIMD];
    __shared__ float4 partL[8][64];
    if (t < Td) erow[t] = emb[(b * Nn + tgt) * Td + t];
    __syncthreads();

    int wv = t >> 6, c = t & 63;         // wv 0..7
    {
        float4 aL = {};
        float4 buf[8];
#pragma unroll
        for (int pp = 0; pp < 8; ++pp)
            buf[pp] = *(const float4*)(Wl + ((wv << 5) + pp) * Td + 4 * c);
#pragma unroll
        for (int i = 0; i < 32; ++i) {
            int k = (wv << 5) + i;
            float4 wlv = buf[i & 7];
            if (i + 8 < 32)
                buf[i & 7] = *(const float4*)(Wl + (k + 8) * Td + 4 * c);
            FMA4(aL, erow[k], wlv);
        }
        partL[wv][c] = aL;
    }
    __syncthreads();

    if (t < Td) {
        int c2 = t >> 2, j = t & 3;
        float acc = bl[t];
#pragma unroll
        for (int w2 = 0; w2 < 8; ++w2) acc += ((const float*)&partL[w2][c2])[j];
        float ah = fmaxf(acc, 0.f);
        lg[t] = ah * snh[b * Td + t];
    }
    __syncthreads();
    if (t < Td) {
        int h = t & 7;
        float mx = -1e30f;
#pragma unroll
        for (int d = 0; d < DIMD; ++d) mx = fmaxf(mx, lg[d * HEADS + h]);
        float se = 0.f;
#pragma unroll
        for (int d = 0; d < DIMD; ++d) se += __expf(lg[d * HEADS + h] - mx);
        float attn = __expf(lg[t] - mx) / se;
        p[t] = attn * shid[b * Td + t];
    }
    __syncthreads();
    if (t < DIMD) {
        float s = 0.f;
#pragma unroll
        for (int hh = 0; hh < HEADS; ++hh) s += p[t * HEADS + hh];
        od[t] = s * (1.f / HEADS);
    }
    __syncthreads();
    if (t < ACTD) {
        float s = ba[t];
#pragma unroll
        for (int d = 0; d < DIMD; ++d) s = fmaf(od[d], Wa[d * ACTD + t], s);
        out[b * ACTD + t] = s;
    }
}

extern "C" void kernel_launch(void* const* d_in, const int* in_sizes, int n_in,
                              void* d_out, int out_size, void* d_ws, size_t ws_size,
                              hipStream_t stream) {
    const float* x   = (const float*)d_in[0];
    const float* adj = (const float*)d_in[1];
    const float* We1 = (const float*)d_in[2];
    const float* be1 = (const float*)d_in[3];
    const float* We2 = (const float*)d_in[4];
    const float* be2 = (const float*)d_in[5];
    const float* Wl  = (const float*)d_in[6];
    const float* bl  = (const float*)d_in[7];
    const float* Wn  = (const float*)d_in[8];
    const float* bn  = (const float*)d_in[9];
    const float* Wh  = (const float*)d_in[10];
    const float* bh  = (const float*)d_in[11];
    const float* Wa  = (const float*)d_in[12];
    const float* ba  = (const float*)d_in[13];
    float* out = (float*)d_out;

    // ws layout: emb f32[B*N*T] (1 MB) | snh f32[B*T] | shid f32[B*T] | dump f32[12288]
    float* emb  = (float*)d_ws;
    float* snh  = emb + Bsz * Nn * Td;
    float* shid = snh + Bsz * Td;
    float* dump = shid + Bsz * Td;

    k_emb<<<dim3(Bsz * Nn / R1), dim3(512), 0, stream>>>(x, We1, be1, We2, be2,
                                                         Wn, Wh, Wl,
                                                         emb, snh, shid, dump);
    k_fused<<<dim3(Nn / R2, Bsz), dim3(1024), 0, stream>>>(adj, emb, Wn, bn, Wh, bh,
                                                           snh, shid);
    k_final<<<dim3(Bsz), dim3(512), 0, stream>>>(x, emb, Wl, bl, snh, shid, Wa, ba, out);
}

// Round 2
// 109.311 us; speedup vs baseline: 1.3960x; 1.3960x over previous
//
#include <hip/hip_runtime.h>

#define Bsz 4
#define Nn  256
#define OBSD 40
#define ACTD 8
#define HEADS 8
#define DIMD 32
#define Td  256
#define R1  2   // rows per block in k_emb  -> grid 512 = 2 blocks/CU
#define R2  2   // m-rows per block in k_fused -> grid 512 = 2 blocks/CU

#define FMA4(accr, s, wv) \
    (accr).x = fmaf((s), (wv).x, (accr).x); \
    (accr).y = fmaf((s), (wv).y, (accr).y); \
    (accr).z = fmaf((s), (wv).z, (accr).z); \
    (accr).w = fmaf((s), (wv).w, (accr).w)

// K1: emb = relu(relu(obs @ We1 + be1) @ We2 + be2), R1=2 rows per block.
// grid = 512 blocks x 512 threads. lb(512,1): no forced VGPR cap; natural
// VGPR (~60) + 18 KB LDS let 2 blocks/CU co-reside = 4 waves/SIMD.
__global__ __launch_bounds__(512, 1) void k_emb(
                      const float* __restrict__ x,
                      const float* __restrict__ We1, const float* __restrict__ be1,
                      const float* __restrict__ We2, const float* __restrict__ be2,
                      float* __restrict__ emb,
                      float* __restrict__ snh, float* __restrict__ shid) {
    int g = blockIdx.x;                  // 0..511
    int t = threadIdx.x;                 // 0..511
    int row0 = g * R1;
    int b = row0 >> 8;
    int n0 = row0 & 255;
    if (g == 0)      { for (int i = t; i < Bsz * Td; i += 512) snh[i]  = 0.f; }
    else if (g == 1) { for (int i = t; i < Bsz * Td; i += 512) shid[i] = 0.f; }

    __shared__ float2 obs_t[OBSD];       // 2 rows per obs-channel (320 B)
    __shared__ float2 h1_t[Td];          // 2 rows per hidden channel (2 KB)
    __shared__ float4 part[8][R1][64];   // [wave][row][colgroup] partials (16 KB)
    if (t < R1 * OBSD) {                 // 80 threads
        int r = t & 1, k = t >> 1;
        ((float*)&obs_t[k])[r] = x[(b * (Nn + 1) + n0 + r) * OBSD + k];
    }
    __syncthreads();

    // Layer 1 (K=40): threads 0..255 own one column each, 8-deep prefetch.
    if (t < Td) {
        float bias1 = be1[t];
        float a0 = bias1, a1 = bias1;
        float wbuf[8];
#pragma unroll
        for (int p = 0; p < 8; ++p) wbuf[p] = We1[p * Td + t];
#pragma unroll
        for (int k = 0; k < OBSD; ++k) {
            float w = wbuf[k & 7];
            if (k + 8 < OBSD) wbuf[k & 7] = We1[(k + 8) * Td + t];
            float2 ov = obs_t[k];
            a0 = fmaf(ov.x, w, a0);
            a1 = fmaf(ov.y, w, a1);
        }
        h1_t[t] = make_float2(fmaxf(a0, 0.f), fmaxf(a1, 0.f));
    }
    __syncthreads();

    // Layer 2: wave wv (0..7) handles k in [32wv, +32); lane c owns cols 4c..4c+3.
    int wv = t >> 6, c = t & 63;
    {
        float4 a2[R1] = {};
        float4 buf[8];
#pragma unroll
        for (int p = 0; p < 8; ++p)
            buf[p] = *(const float4*)(We2 + ((wv << 5) + p) * Td + 4 * c);
#pragma unroll
        for (int i = 0; i < 32; ++i) {
            int k = (wv << 5) + i;
            float4 wvv = buf[i & 7];
            if (i + 8 < 32)
                buf[i & 7] = *(const float4*)(We2 + (k + 8) * Td + 4 * c);
            float2 hv = h1_t[k];
            FMA4(a2[0], hv.x, wvv);
            FMA4(a2[1], hv.y, wvv);
        }
#pragma unroll
        for (int r = 0; r < R1; ++r) part[wv][r][c] = a2[r];
    }
    __syncthreads();

    if (t < Td) {
        int c2 = t >> 2, j = t & 3;
#pragma unroll
        for (int r = 0; r < R1; ++r) {
            float v = be2[t];
#pragma unroll
            for (int w2 = 0; w2 < 8; ++w2) v += ((const float*)&part[w2][r][c2])[j];
            emb[(row0 + r) * Td + t] = fmaxf(v, 0.f);
        }
    }
}

// K2: fused ne + Wn/Wh column-sum, R2=2 m-rows per block.
// grid = (N/R2, B) = (128, 4) = 512 blocks x 512 threads. lb(512,1): natural
// VGPR (~90) + 36 KB LDS -> 2 blocks/CU = 4 waves/SIMD (grid was the round-0
// limiter at 256 blocks). Per-block L2 traffic unchanged; total doubles but
// stays ~11 us of aggregate L2 BW vs the ~30 us of latency being recovered.
__global__ __launch_bounds__(512, 1) void k_fused(
                        const float* __restrict__ adj, const float* __restrict__ emb,
                        const float* __restrict__ Wn, const float* __restrict__ bn,
                        const float* __restrict__ Wh, const float* __restrict__ bh,
                        float* __restrict__ snh, float* __restrict__ shid) {
    int g = blockIdx.x, b = blockIdx.y;
    int t = threadIdx.x;                 // 0..511
    int m0 = g * R2;
    __shared__ float2 arow_t[Nn];        // 2 KB
    __shared__ float2 nrow_t[Td];        // 2 KB
    __shared__ float4 partN[8][R2][64];  // 16 KB
    __shared__ float4 partH[8][R2][64];  // 16 KB   (total 36 KB)
    if (t < Td)
        arow_t[t] = make_float2(adj[(m0 + 0) * Nn + t], adj[(m0 + 1) * Nn + t]);
    __syncthreads();

    int wv = t >> 6, c = t & 63;         // wv 0..7
    const float* eb = emb + b * Nn * Td;

    // Phase 1: ne. Wave wv sums n in [32wv, +32); 8-deep prefetch.
    {
        float4 aN[R2] = {};
        float4 buf[8];
#pragma unroll
        for (int p = 0; p < 8; ++p)
            buf[p] = *(const float4*)(eb + ((wv << 5) + p) * Td + 4 * c);
#pragma unroll
        for (int i = 0; i < 32; ++i) {
            int n = (wv << 5) + i;
            float4 ev = buf[i & 7];
            if (i + 8 < 32)
                buf[i & 7] = *(const float4*)(eb + (n + 8) * Td + 4 * c);
            float2 ar = arow_t[n];
            FMA4(aN[0], ar.x, ev);
            FMA4(aN[1], ar.y, ev);
        }
#pragma unroll
        for (int r = 0; r < R2; ++r) partN[wv][r][c] = aN[r];
    }
    __syncthreads();
    if (t < Td) {
        int c2 = t >> 2, j = t & 3;
        float nr[R2];
#pragma unroll
        for (int r = 0; r < R2; ++r) {
            float v = 0.f;
#pragma unroll
            for (int w2 = 0; w2 < 8; ++w2) v += ((const float*)&partN[w2][r][c2])[j];
            nr[r] = v;
        }
        nrow_t[t] = make_float2(nr[0], nr[1]);
    }
    __syncthreads();

    // Phase 2: Wn/Wh dual stream; wave wv handles k in [32wv, +32); 4+4 prefetch.
    {
        float4 sN[R2] = {};
        float4 sH[R2] = {};
        float4 bufN[4], bufH[4];
#pragma unroll
        for (int p = 0; p < 4; ++p) {
            int k = (wv << 5) + p;
            bufN[p] = *(const float4*)(Wn + k * Td + 4 * c);
            bufH[p] = *(const float4*)(Wh + k * Td + 4 * c);
        }
#pragma unroll
        for (int i = 0; i < 32; ++i) {
            int k = (wv << 5) + i;
            float4 wn4 = bufN[i & 3];
            float4 wh4 = bufH[i & 3];
            if (i + 4 < 32) {
                bufN[i & 3] = *(const float4*)(Wn + (k + 4) * Td + 4 * c);
                bufH[i & 3] = *(const float4*)(Wh + (k + 4) * Td + 4 * c);
            }
            float2 nv = nrow_t[k];
            FMA4(sN[0], nv.x, wn4);  FMA4(sH[0], nv.x, wh4);
            FMA4(sN[1], nv.y, wn4);  FMA4(sH[1], nv.y, wh4);
        }
#pragma unroll
        for (int r = 0; r < R2; ++r) { partN[wv][r][c] = sN[r]; partH[wv][r][c] = sH[r]; }
    }
    __syncthreads();

    // Reduce over 8 waves (pre-relu), bias, relu, sum rows, one atomic per col.
    if (t < Td) {
        int c2 = t >> 2, j = t & 3;
        float bnt = bn[t], bht = bh[t];
        float rs1 = 0.f, rs2 = 0.f;
#pragma unroll
        for (int r = 0; r < R2; ++r) {
            float v1 = bnt, v2 = bht;
#pragma unroll
            for (int w2 = 0; w2 < 8; ++w2) {
                v1 += ((const float*)&partN[w2][r][c2])[j];
                v2 += ((const float*)&partH[w2][r][c2])[j];
            }
            rs1 += fmaxf(v1, 0.f);
            rs2 += fmaxf(v2, 0.f);
        }
        atomicAdd(&snh[b * Td + t], rs1);
        atomicAdd(&shid[b * Td + t], rs2);
    }
}

// K3: per-batch target row -> ah -> softmax over DIM per head -> mean -> Wa
// 512 threads: 8-way k-split on the Wl reduction.
__global__ __launch_bounds__(512, 1) void k_final(
                        const float* __restrict__ x, const float* __restrict__ emb,
                        const float* __restrict__ Wl, const float* __restrict__ bl,
                        const float* __restrict__ snh, const float* __restrict__ shid,
                        const float* __restrict__ Wa, const float* __restrict__ ba,
                        float* __restrict__ out) {
    int b = blockIdx.x;
    int t = threadIdx.x;                 // 0..511
    int tgt = (int)x[(b * (Nn + 1) + Nn) * OBSD + 0];
    tgt = tgt < 0 ? 0 : (tgt > Nn - 1 ? Nn - 1 : tgt);
    __shared__ float erow[Td], lg[Td], p[Td], od[DIMD];
    __shared__ float4 partL[8][64];
    if (t < Td) erow[t] = emb[(b * Nn + tgt) * Td + t];
    __syncthreads();

    int wv = t >> 6, c = t & 63;         // wv 0..7
    {
        float4 aL = {};
        float4 buf[8];
#pragma unroll
        for (int pp = 0; pp < 8; ++pp)
            buf[pp] = *(const float4*)(Wl + ((wv << 5) + pp) * Td + 4 * c);
#pragma unroll
        for (int i = 0; i < 32; ++i) {
            int k = (wv << 5) + i;
            float4 wlv = buf[i & 7];
            if (i + 8 < 32)
                buf[i & 7] = *(const float4*)(Wl + (k + 8) * Td + 4 * c);
            FMA4(aL, erow[k], wlv);
        }
        partL[wv][c] = aL;
    }
    __syncthreads();

    if (t < Td) {
        int c2 = t >> 2, j = t & 3;
        float acc = bl[t];
#pragma unroll
        for (int w2 = 0; w2 < 8; ++w2) acc += ((const float*)&partL[w2][c2])[j];
        float ah = fmaxf(acc, 0.f);
        lg[t] = ah * snh[b * Td + t];
    }
    __syncthreads();
    if (t < Td) {
        int h = t & 7;
        float mx = -1e30f;
#pragma unroll
        for (int d = 0; d < DIMD; ++d) mx = fmaxf(mx, lg[d * HEADS + h]);
        float se = 0.f;
#pragma unroll
        for (int d = 0; d < DIMD; ++d) se += __expf(lg[d * HEADS + h] - mx);
        float attn = __expf(lg[t] - mx) / se;
        p[t] = attn * shid[b * Td + t];
    }
    __syncthreads();
    if (t < DIMD) {
        float s = 0.f;
#pragma unroll
        for (int hh = 0; hh < HEADS; ++hh) s += p[t * HEADS + hh];
        od[t] = s * (1.f / HEADS);
    }
    __syncthreads();
    if (t < ACTD) {
        float s = ba[t];
#pragma unroll
        for (int d = 0; d < DIMD; ++d) s = fmaf(od[d], Wa[d * ACTD + t], s);
        out[b * ACTD + t] = s;
    }
}

extern "C" void kernel_launch(void* const* d_in, const int* in_sizes, int n_in,
                              void* d_out, int out_size, void* d_ws, size_t ws_size,
                              hipStream_t stream) {
    const float* x   = (const float*)d_in[0];
    const float* adj = (const float*)d_in[1];
    const float* We1 = (const float*)d_in[2];
    const float* be1 = (const float*)d_in[3];
    const float* We2 = (const float*)d_in[4];
    const float* be2 = (const float*)d_in[5];
    const float* Wl  = (const float*)d_in[6];
    const float* bl  = (const float*)d_in[7];
    const float* Wn  = (const float*)d_in[8];
    const float* bn  = (const float*)d_in[9];
    const float* Wh  = (const float*)d_in[10];
    const float* bh  = (const float*)d_in[11];
    const float* Wa  = (const float*)d_in[12];
    const float* ba  = (const float*)d_in[13];
    float* out = (float*)d_out;

    // ws layout: emb f32[B*N*T] (1 MB) | snh f32[B*T] | shid f32[B*T]
    float* emb  = (float*)d_ws;
    float* snh  = emb + Bsz * Nn * Td;
    float* shid = snh + Bsz * Td;

    k_emb<<<dim3(Bsz * Nn / R1), dim3(512), 0, stream>>>(x, We1, be1, We2, be2,
                                                         emb, snh, shid);
    k_fused<<<dim3(Nn / R2, Bsz), dim3(512), 0, stream>>>(adj, emb, Wn, bn, Wh, bh,
                                                          snh, shid);
    k_final<<<dim3(Bsz), dim3(512), 0, stream>>>(x, emb, Wl, bl, snh, shid, Wa, ba, out);
}

// Round 3
// 102.571 us; speedup vs baseline: 1.4877x; 1.0657x over previous
//
#include <hip/hip_runtime.h>

#define Bsz 4
#define Nn  256
#define OBSD 40
#define ACTD 8
#define HEADS 8
#define DIMD 32
#define Td  256
#define R   4   // rows per block in k_emb (round-0 config)

#define FMA4(accr, s, wv) \
    (accr).x = fmaf((s), (wv).x, (accr).x); \
    (accr).y = fmaf((s), (wv).y, (accr).y); \
    (accr).z = fmaf((s), (wv).z, (accr).z); \
    (accr).w = fmaf((s), (wv).w, (accr).w)

// K1: emb = relu(relu(obs @ We1 + be1) @ We2 + be2), R=4 rows per block.
// grid = 256 blocks x 512 threads (round-0 verified config).
__global__ __launch_bounds__(512, 1) void k_emb(
                      const float* __restrict__ x,
                      const float* __restrict__ We1, const float* __restrict__ be1,
                      const float* __restrict__ We2, const float* __restrict__ be2,
                      float* __restrict__ emb,
                      float* __restrict__ snh, float* __restrict__ shid) {
    int g = blockIdx.x;
    int t = threadIdx.x;                 // 0..511
    int row0 = g * R;
    int b = row0 >> 8;
    int n0 = row0 & 255;
    if (g == 0)      { for (int i = t; i < Bsz * Td; i += 512) snh[i]  = 0.f; }
    else if (g == 1) { for (int i = t; i < Bsz * Td; i += 512) shid[i] = 0.f; }

    __shared__ float4 obs_t[OBSD];       // 4 rows per obs-channel
    __shared__ float4 h1_t[Td];          // 4 rows per hidden channel
    __shared__ float4 part[8][R][64];    // [wave][row][colgroup] partials (32 KB)
    if (t < R * OBSD) {
        int r = t & (R - 1), k = t >> 2;
        ((float*)&obs_t[k])[r] = x[(b * (Nn + 1) + n0 + r) * OBSD + k];
    }
    __syncthreads();

    // Layer 1 (K=40): threads 0..255 own one column each, 8-deep prefetch.
    if (t < Td) {
        float bias1 = be1[t];
        float a1[R] = {bias1, bias1, bias1, bias1};
        float wbuf[8];
#pragma unroll
        for (int p = 0; p < 8; ++p) wbuf[p] = We1[p * Td + t];
#pragma unroll
        for (int k = 0; k < OBSD; ++k) {
            float w = wbuf[k & 7];
            if (k + 8 < OBSD) wbuf[k & 7] = We1[(k + 8) * Td + t];
            float4 ov = obs_t[k];
            a1[0] = fmaf(ov.x, w, a1[0]);
            a1[1] = fmaf(ov.y, w, a1[1]);
            a1[2] = fmaf(ov.z, w, a1[2]);
            a1[3] = fmaf(ov.w, w, a1[3]);
        }
        h1_t[t] = make_float4(fmaxf(a1[0], 0.f), fmaxf(a1[1], 0.f),
                              fmaxf(a1[2], 0.f), fmaxf(a1[3], 0.f));
    }
    __syncthreads();

    // Layer 2: wave wv (0..7) handles k in [32wv, +32); lane c owns cols 4c..4c+3.
    int wv = t >> 6, c = t & 63;
    {
        float4 a2[R] = {};
        float4 buf[8];
#pragma unroll
        for (int p = 0; p < 8; ++p)
            buf[p] = *(const float4*)(We2 + ((wv << 5) + p) * Td + 4 * c);
#pragma unroll
        for (int i = 0; i < 32; ++i) {
            int k = (wv << 5) + i;
            float4 wvv = buf[i & 7];
            if (i + 8 < 32)
                buf[i & 7] = *(const float4*)(We2 + (k + 8) * Td + 4 * c);
            float4 hv = h1_t[k];
            FMA4(a2[0], hv.x, wvv);
            FMA4(a2[1], hv.y, wvv);
            FMA4(a2[2], hv.z, wvv);
            FMA4(a2[3], hv.w, wvv);
        }
#pragma unroll
        for (int r = 0; r < R; ++r) part[wv][r][c] = a2[r];
    }
    __syncthreads();

    if (t < Td) {
        int c2 = t >> 2, j = t & 3;
#pragma unroll
        for (int r = 0; r < R; ++r) {
            float v = be2[t];
#pragma unroll
            for (int w2 = 0; w2 < 8; ++w2) v += ((const float*)&part[w2][r][c2])[j];
            emb[(row0 + r) * Td + t] = fmaxf(v, 0.f);
        }
    }
}

// K2a: ne[b] = adj @ emb[b]. Tiled GEMM, tile 16(m) x 64(t), K = 256.
// grid = (16 m-tiles, 4 t-tiles, 4 b) = 256 blocks x 512 threads.
// Per block: adj panel 16 KB (LDS) + emb panel 64 KB (global, prefetched)
// -> 20 MB aggregate (vs ~70 MB share of old k_fused phase 1).
__global__ __launch_bounds__(512, 1) void k_ne(
                        const float* __restrict__ adj, const float* __restrict__ emb,
                        float* __restrict__ ne) {
    int mt = blockIdx.x, tt = blockIdx.y, b = blockIdx.z;
    int t = threadIdx.x;                 // 0..511
    int m0 = mt << 4, t0 = tt << 6;
    __shared__ float A_lds[16][260];     // adj rows m0..m0+15, padded (16.6 KB)
    __shared__ float4 part[8][4][16][4]; // [wv][rq][cg][j] (32 KB)

    // Stage A: thread t loads adj[m0 + (t>>5)][8*(t&31) .. +7] (coalesced).
    {
        int r = t >> 5, kb = (t & 31) << 3;
        const float* Ar = adj + (m0 + r) * Nn + kb;
        float4 a0 = *(const float4*)(Ar);
        float4 a1 = *(const float4*)(Ar + 4);
        *(float4*)&A_lds[r][kb] = a0;
        *(float4*)&A_lds[r][kb + 4] = a1;
    }
    __syncthreads();

    // Main loop: wave wv owns k in [32wv, +32); lane: cg = c&15 (cols 4cg..+3),
    // rq = c>>4 (rows 4rq..4rq+3). B (emb) from global, 8-deep prefetch.
    int wv = t >> 6, c = t & 63;
    int cg = c & 15, rq = c >> 4;
    const float* Bp = emb + b * Nn * Td + t0 + (cg << 2);
    {
        float4 acc[4] = {};
        float4 buf[8];
#pragma unroll
        for (int p = 0; p < 8; ++p)
            buf[p] = *(const float4*)(Bp + ((wv << 5) + p) * Td);
#pragma unroll
        for (int i = 0; i < 32; ++i) {
            int k = (wv << 5) + i;
            float4 bv = buf[i & 7];
            if (i + 8 < 32)
                buf[i & 7] = *(const float4*)(Bp + (k + 8) * Td);
            float a0 = A_lds[(rq << 2) + 0][k];
            float a1 = A_lds[(rq << 2) + 1][k];
            float a2 = A_lds[(rq << 2) + 2][k];
            float a3 = A_lds[(rq << 2) + 3][k];
            FMA4(acc[0], a0, bv);
            FMA4(acc[1], a1, bv);
            FMA4(acc[2], a2, bv);
            FMA4(acc[3], a3, bv);
        }
#pragma unroll
        for (int j = 0; j < 4; ++j) part[wv][rq][cg][j] = acc[j];
    }
    __syncthreads();

    // Reduce over 8 waves; each thread writes outputs o = t and o = t + 512.
    float* nb = ne + b * Nn * Td;
#pragma unroll
    for (int h = 0; h < 2; ++h) {
        int o = t + (h << 9);
        int r = o >> 6, cc = o & 63;
        int rq2 = r >> 2, rj = r & 3, cg2 = cc >> 2, ci = cc & 3;
        float v = 0.f;
#pragma unroll
        for (int w2 = 0; w2 < 8; ++w2)
            v += ((const float*)&part[w2][rq2][cg2][rj])[ci];
        nb[(m0 + r) * Td + t0 + cc] = v;
    }
}

// K2b: snh += sum_m relu(ne@Wn + bn), shid += sum_m relu(ne@Wh + bh).
// Same tiling as k_ne, dual B streams, fused relu + column-sum epilogue,
// one atomicAdd per column per block. 37 MB aggregate (vs 134 MB before).
__global__ __launch_bounds__(512, 1) void k_snh(
                        const float* __restrict__ ne,
                        const float* __restrict__ Wn, const float* __restrict__ bn,
                        const float* __restrict__ Wh, const float* __restrict__ bh,
                        float* __restrict__ snh, float* __restrict__ shid) {
    int mt = blockIdx.x, tt = blockIdx.y, b = blockIdx.z;
    int t = threadIdx.x;                 // 0..511
    int m0 = mt << 4, t0 = tt << 6;
    __shared__ float A_lds[16][260];      // ne rows m0..m0+15 (16.6 KB)
    __shared__ float4 partN[8][4][16][4]; // 32 KB
    __shared__ float4 partH[8][4][16][4]; // 32 KB
    __shared__ float redN[16][64];        // 4 KB
    __shared__ float redH[16][64];        // 4 KB   (total ~89 KB)

    {
        int r = t >> 5, kb = (t & 31) << 3;
        const float* Ar = ne + b * Nn * Td + (m0 + r) * Td + kb;
        float4 a0 = *(const float4*)(Ar);
        float4 a1 = *(const float4*)(Ar + 4);
        *(float4*)&A_lds[r][kb] = a0;
        *(float4*)&A_lds[r][kb + 4] = a1;
    }
    __syncthreads();

    int wv = t >> 6, c = t & 63;
    int cg = c & 15, rq = c >> 4;
    const float* BpN = Wn + t0 + (cg << 2);
    const float* BpH = Wh + t0 + (cg << 2);
    {
        float4 accN[4] = {};
        float4 accH[4] = {};
        float4 bufN[4], bufH[4];
#pragma unroll
        for (int p = 0; p < 4; ++p) {
            int k = (wv << 5) + p;
            bufN[p] = *(const float4*)(BpN + k * Td);
            bufH[p] = *(const float4*)(BpH + k * Td);
        }
#pragma unroll
        for (int i = 0; i < 32; ++i) {
            int k = (wv << 5) + i;
            float4 wn4 = bufN[i & 3];
            float4 wh4 = bufH[i & 3];
            if (i + 4 < 32) {
                bufN[i & 3] = *(const float4*)(BpN + (k + 4) * Td);
                bufH[i & 3] = *(const float4*)(BpH + (k + 4) * Td);
            }
            float a0 = A_lds[(rq << 2) + 0][k];
            float a1 = A_lds[(rq << 2) + 1][k];
            float a2 = A_lds[(rq << 2) + 2][k];
            float a3 = A_lds[(rq << 2) + 3][k];
            FMA4(accN[0], a0, wn4);  FMA4(accH[0], a0, wh4);
            FMA4(accN[1], a1, wn4);  FMA4(accH[1], a1, wh4);
            FMA4(accN[2], a2, wn4);  FMA4(accH[2], a2, wh4);
            FMA4(accN[3], a3, wn4);  FMA4(accH[3], a3, wh4);
        }
#pragma unroll
        for (int j = 0; j < 4; ++j) { partN[wv][rq][cg][j] = accN[j]; partH[wv][rq][cg][j] = accH[j]; }
    }
    __syncthreads();

    // Reduce over 8 waves, add bias, relu; stash in red[r][c].
#pragma unroll
    for (int h = 0; h < 2; ++h) {
        int o = t + (h << 9);
        int r = o >> 6, cc = o & 63;
        int rq2 = r >> 2, rj = r & 3, cg2 = cc >> 2, ci = cc & 3;
        float vN = bn[t0 + cc], vH = bh[t0 + cc];
#pragma unroll
        for (int w2 = 0; w2 < 8; ++w2) {
            vN += ((const float*)&partN[w2][rq2][cg2][rj])[ci];
            vH += ((const float*)&partH[w2][rq2][cg2][rj])[ci];
        }
        redN[r][cc] = fmaxf(vN, 0.f);
        redH[r][cc] = fmaxf(vH, 0.f);
    }
    __syncthreads();

    // Column-sum over the 16 tile rows; one atomic per column per stream.
    if (t < 64) {
        float s = 0.f;
#pragma unroll
        for (int r = 0; r < 16; ++r) s += redN[r][t];
        atomicAdd(&snh[b * Td + t0 + t], s);
    } else if (t < 128) {
        int cc = t - 64;
        float s = 0.f;
#pragma unroll
        for (int r = 0; r < 16; ++r) s += redH[r][cc];
        atomicAdd(&shid[b * Td + t0 + cc], s);
    }
}

// K3: per-batch target row -> ah -> softmax over DIM per head -> mean -> Wa
// 512 threads: 8-way k-split on the Wl reduction (round-2 verified).
__global__ __launch_bounds__(512, 1) void k_final(
                        const float* __restrict__ x, const float* __restrict__ emb,
                        const float* __restrict__ Wl, const float* __restrict__ bl,
                        const float* __restrict__ snh, const float* __restrict__ shid,
                        const float* __restrict__ Wa, const float* __restrict__ ba,
                        float* __restrict__ out) {
    int b = blockIdx.x;
    int t = threadIdx.x;                 // 0..511
    int tgt = (int)x[(b * (Nn + 1) + Nn) * OBSD + 0];
    tgt = tgt < 0 ? 0 : (tgt > Nn - 1 ? Nn - 1 : tgt);
    __shared__ float erow[Td], lg[Td], p[Td], od[DIMD];
    __shared__ float4 partL[8][64];
    if (t < Td) erow[t] = emb[(b * Nn + tgt) * Td + t];
    __syncthreads();

    int wv = t >> 6, c = t & 63;         // wv 0..7
    {
        float4 aL = {};
        float4 buf[8];
#pragma unroll
        for (int pp = 0; pp < 8; ++pp)
            buf[pp] = *(const float4*)(Wl + ((wv << 5) + pp) * Td + 4 * c);
#pragma unroll
        for (int i = 0; i < 32; ++i) {
            int k = (wv << 5) + i;
            float4 wlv = buf[i & 7];
            if (i + 8 < 32)
                buf[i & 7] = *(const float4*)(Wl + (k + 8) * Td + 4 * c);
            FMA4(aL, erow[k], wlv);
        }
        partL[wv][c] = aL;
    }
    __syncthreads();

    if (t < Td) {
        int c2 = t >> 2, j = t & 3;
        float acc = bl[t];
#pragma unroll
        for (int w2 = 0; w2 < 8; ++w2) acc += ((const float*)&partL[w2][c2])[j];
        float ah = fmaxf(acc, 0.f);
        lg[t] = ah * snh[b * Td + t];
    }
    __syncthreads();
    if (t < Td) {
        int h = t & 7;
        float mx = -1e30f;
#pragma unroll
        for (int d = 0; d < DIMD; ++d) mx = fmaxf(mx, lg[d * HEADS + h]);
        float se = 0.f;
#pragma unroll
        for (int d = 0; d < DIMD; ++d) se += __expf(lg[d * HEADS + h] - mx);
        float attn = __expf(lg[t] - mx) / se;
        p[t] = attn * shid[b * Td + t];
    }
    __syncthreads();
    if (t < DIMD) {
        float s = 0.f;
#pragma unroll
        for (int hh = 0; hh < HEADS; ++hh) s += p[t * HEADS + hh];
        od[t] = s * (1.f / HEADS);
    }
    __syncthreads();
    if (t < ACTD) {
        float s = ba[t];
#pragma unroll
        for (int d = 0; d < DIMD; ++d) s = fmaf(od[d], Wa[d * ACTD + t], s);
        out[b * ACTD + t] = s;
    }
}

extern "C" void kernel_launch(void* const* d_in, const int* in_sizes, int n_in,
                              void* d_out, int out_size, void* d_ws, size_t ws_size,
                              hipStream_t stream) {
    const float* x   = (const float*)d_in[0];
    const float* adj = (const float*)d_in[1];
    const float* We1 = (const float*)d_in[2];
    const float* be1 = (const float*)d_in[3];
    const float* We2 = (const float*)d_in[4];
    const float* be2 = (const float*)d_in[5];
    const float* Wl  = (const float*)d_in[6];
    const float* bl  = (const float*)d_in[7];
    const float* Wn  = (const float*)d_in[8];
    const float* bn  = (const float*)d_in[9];
    const float* Wh  = (const float*)d_in[10];
    const float* bh  = (const float*)d_in[11];
    const float* Wa  = (const float*)d_in[12];
    const float* ba  = (const float*)d_in[13];
    float* out = (float*)d_out;

    // ws layout: emb f32[B*N*T] (1 MB) | ne f32[B*N*T] (1 MB) | snh | shid
    float* emb  = (float*)d_ws;
    float* ne   = emb + Bsz * Nn * Td;
    float* snh  = ne  + Bsz * Nn * Td;
    float* shid = snh + Bsz * Td;

    k_emb<<<dim3(Bsz * Nn / R), dim3(512), 0, stream>>>(x, We1, be1, We2, be2,
                                                        emb, snh, shid);
    k_ne<<<dim3(16, 4, Bsz), dim3(512), 0, stream>>>(adj, emb, ne);
    k_snh<<<dim3(16, 4, Bsz), dim3(512), 0, stream>>>(ne, Wn, bn, Wh, bh, snh, shid);
    k_final<<<dim3(Bsz), dim3(512), 0, stream>>>(x, emb, Wl, bl, snh, shid, Wa, ba, out);
}